// Round 1
// baseline (1088.517 us; speedup 1.0000x reference)
//
#include <hip/hip_runtime.h>

#define N_ 16
#define C_ 256
#define H_ 128
#define W_ 128
#define O_ 256
#define WELEMS (O_ * C_ * 9)   // 589824

typedef short bf16x8 __attribute__((ext_vector_type(8)));
typedef float f32x4 __attribute__((ext_vector_type(4)));

__global__ void absum_k(const float* __restrict__ w, float* __restrict__ sum) {
  int tid = blockIdx.x * blockDim.x + threadIdx.x;
  float s = 0.f;
  for (int i = tid; i < WELEMS; i += gridDim.x * blockDim.x) s += fabsf(w[i]);
  #pragma unroll
  for (int off = 32; off > 0; off >>= 1) s += __shfl_down(s, off, 64);
  if ((threadIdx.x & 63) == 0) atomicAdd(sum, s);
}

__global__ void quant_k(const float* __restrict__ w, const float* __restrict__ sum,
                        unsigned short* __restrict__ wp) {
  int i = blockIdx.x * blockDim.x + threadIdx.x;
  if (i >= WELEMS) return;
  float scale = fmaxf(sum[0] * (1.0f / (float)WELEMS), 1e-5f);
  int kk = i % 9;              // ky*3+kx
  int c = (i / 9) % C_;
  int o = i / (9 * C_);
  float q = rintf(w[i] / scale);          // rint = round-half-even, matches jnp.round
  q = fminf(1.f, fmaxf(-1.f, q));
  wp[(kk * O_ + o) * C_ + c] = __builtin_bit_cast(unsigned short, (__bf16)q);
}

// Block: 128 o (ohalf) x [2 output rows x 128 w] spatial. 512 threads = 8 waves (2 o x 4 spatial).
// LDS X tile: [4 input rows][130 w'][32 c] bf16, line = 64B, XOR-swizzled on bits 4-5 by w'.
__global__ void conv_k(const float* __restrict__ x,
                       const float* __restrict__ bias,
                       const unsigned short* __restrict__ wp,
                       const float* __restrict__ sum,
                       float* __restrict__ out) {
  __shared__ __attribute__((aligned(64))) unsigned char Xs[520 * 64];

  const int bid = blockIdx.x;
  const int pid = bid >> 1, ohalf = bid & 1;
  // XCD-aware swizzle on o-pair id (1024 pairs, 8 XCDs, bijective since 1024%8==0)
  const int spid = (pid & 7) * 128 + (pid >> 3);
  const int n = spid >> 6;
  const int h0 = (spid & 63) << 1;
  const int o_blk = ohalf << 7;

  const int tid = threadIdx.x;

  // zero the padding columns w'=0 and w'=129 once (all 32 c, 4 rows)
  if (tid < 128) {
    const int li = tid >> 5, sel = (tid >> 4) & 1, word = tid & 15;
    const int wq = sel ? 129 : 0;
    *(int*)(Xs + (li * 130 + wq) * 64 + word * 4) = 0;
  }

  const int wid = tid >> 6, lane = tid & 63;
  const int l15 = lane & 15, g = lane >> 4;
  const int wmo = (wid >> 2) << 6;           // wave o-offset: 0 or 64
  const int wsid = wid & 3, r = wsid >> 1, wbase = (wsid & 1) << 6;

  f32x4 acc[4][4];
  #pragma unroll
  for (int i = 0; i < 4; ++i) {
    #pragma unroll
    for (int j = 0; j < 4; ++j) acc[i][j] = (f32x4){0.f, 0.f, 0.f, 0.f};
  }

  const float* xn = x + (long)n * (C_ * H_ * W_);

  for (int c0 = 0; c0 < C_; c0 += 32) {
    // ---- stage X chunk: 4 rows x 128 w x 32 c, f32 -> bf16, swizzled scalar writes
    #pragma unroll
    for (int it = 0; it < 8; ++it) {
      const int T = tid + (it << 9);          // 0..4095
      const int w4 = T & 31, cl = (T >> 5) & 31, li = T >> 10;
      const int h_in = h0 - 1 + li;
      float4 v = make_float4(0.f, 0.f, 0.f, 0.f);
      if ((unsigned)h_in < (unsigned)H_)
        v = *(const float4*)(xn + ((c0 + cl) * H_ + h_in) * W_ + (w4 << 2));
      const float vv[4] = {v.x, v.y, v.z, v.w};
      #pragma unroll
      for (int j = 0; j < 4; ++j) {
        const int wq = (w4 << 2) + 1 + j;     // w' = w_in + 1
        const int byte_off = (li * 130 + wq) * 64 + ((cl * 2) ^ (((wq >> 1) & 3) << 4));
        *(unsigned short*)(Xs + byte_off) = __builtin_bit_cast(unsigned short, (__bf16)vv[j]);
      }
    }
    __syncthreads();

    // ---- compute: 9 kernel taps x (4 mi x 4 ni) MFMA, K=32 (this c-chunk)
    #pragma unroll
    for (int kk = 0; kk < 9; ++kk) {
      const int ky = kk / 3, kx = kk - ky * 3;
      const int li = r + ky;
      const unsigned short* abase =
          wp + ((kk * O_ + o_blk + wmo + l15) * C_) + c0 + (g << 3);
      bf16x8 a[4];
      #pragma unroll
      for (int mi = 0; mi < 4; ++mi)
        a[mi] = *(const bf16x8*)(abase + (mi << 4) * C_);
      #pragma unroll
      for (int ni = 0; ni < 4; ++ni) {
        const int wq = wbase + (ni << 4) + l15 + kx;   // LDS line = input col + 1
        const int byte_off = (li * 130 + wq) * 64 + ((g << 4) ^ (((wq >> 1) & 3) << 4));
        const bf16x8 b = *(const bf16x8*)(Xs + byte_off);
        #pragma unroll
        for (int mi = 0; mi < 4; ++mi)
          acc[mi][ni] = __builtin_amdgcn_mfma_f32_16x16x32_bf16(a[mi], b, acc[mi][ni], 0, 0, 0);
      }
    }
    __syncthreads();
  }

  // ---- epilogue: out = scale*acc + bias. C/D layout: col = lane&15 (w), row = (lane>>4)*4+q (o)
  const float scale = fmaxf(sum[0] * (1.0f / (float)WELEMS), 1e-5f);
  const int h_out = h0 + r;
  #pragma unroll
  for (int mi = 0; mi < 4; ++mi) {
    #pragma unroll
    for (int q = 0; q < 4; ++q) {
      const int o = o_blk + wmo + (mi << 4) + (g << 2) + q;
      const float bv = bias[o];
      float* orow = out + ((long)n * O_ + o) * (H_ * W_) + h_out * W_;
      #pragma unroll
      for (int ni = 0; ni < 4; ++ni) {
        const int wc = wbase + (ni << 4) + l15;
        orow[wc] = acc[mi][ni][q] * scale + bv;
      }
    }
  }
}

extern "C" void kernel_launch(void* const* d_in, const int* in_sizes, int n_in,
                              void* d_out, int out_size, void* d_ws, size_t ws_size,
                              hipStream_t stream) {
  const float* x = (const float*)d_in[0];
  const float* w = (const float*)d_in[1];
  const float* bias = (const float*)d_in[2];
  float* out = (float*)d_out;
  float* sum = (float*)d_ws;
  unsigned short* wp = (unsigned short*)((char*)d_ws + 16);

  hipMemsetAsync(d_ws, 0, 4, stream);
  absum_k<<<256, 256, 0, stream>>>(w, sum);
  quant_k<<<WELEMS / 256, 256, 0, stream>>>(w, sum, wp);
  conv_k<<<2048, 512, 0, stream>>>(x, bias, wp, sum, out);
}

// Round 2
// 627.719 us; speedup vs baseline: 1.7341x; 1.7341x over previous
//
#include <hip/hip_runtime.h>

#define N_ 16
#define C_ 256
#define H_ 128
#define W_ 128
#define O_ 256
#define HW_ (H_ * W_)
#define WELEMS (O_ * C_ * 9)   // 589824

// LDS line stride: 80 bytes (40 bf16; 32 used). 80/16 = 5 is coprime with the
// 8 16B bank-groups -> both b128 writes (lane=w) and b128 reads (lane=wq)
// distribute 2-way max across banks. No XOR swizzle needed.
#define LSTRIDE 80

typedef short bf16x8 __attribute__((ext_vector_type(8)));
typedef float f32x4 __attribute__((ext_vector_type(4)));

__global__ void absum_k(const float* __restrict__ w, float* __restrict__ sum) {
  int tid = blockIdx.x * blockDim.x + threadIdx.x;
  float s = 0.f;
  for (int i = tid; i < WELEMS; i += gridDim.x * blockDim.x) s += fabsf(w[i]);
  #pragma unroll
  for (int off = 32; off > 0; off >>= 1) s += __shfl_down(s, off, 64);
  if ((threadIdx.x & 63) == 0) atomicAdd(sum, s);
}

__global__ void quant_k(const float* __restrict__ w, const float* __restrict__ sum,
                        unsigned short* __restrict__ wp) {
  int i = blockIdx.x * blockDim.x + threadIdx.x;
  if (i >= WELEMS) return;
  float scale = fmaxf(sum[0] * (1.0f / (float)WELEMS), 1e-5f);
  int kk = i % 9;              // ky*3+kx
  int c = (i / 9) % C_;
  int o = i / (9 * C_);
  float q = rintf(w[i] / scale);          // rint = round-half-even, matches jnp.round
  q = fminf(1.f, fmaxf(-1.f, q));
  wp[(kk * O_ + o) * C_ + c] = __builtin_bit_cast(unsigned short, (__bf16)q);
}

// Block: 128 o (ohalf) x [2 output rows x 128 w] spatial. 512 threads = 8 waves (2 o x 4 spatial).
// LDS X tile: [4 input rows][130 w'][32 c] bf16, line stride 80B.
__global__ void __launch_bounds__(512, 4)
conv_k(const float* __restrict__ x,
       const float* __restrict__ bias,
       const unsigned short* __restrict__ wp,
       const float* __restrict__ sum,
       float* __restrict__ out) {
  __shared__ __attribute__((aligned(128))) unsigned char Xs[4 * 130 * LSTRIDE];

  const int bid = blockIdx.x;
  const int pid = bid >> 1, ohalf = bid & 1;
  // XCD-aware swizzle on o-pair id (1024 pairs, 8 XCDs, bijective since 1024%8==0)
  const int spid = (pid & 7) * 128 + (pid >> 3);
  const int n = spid >> 6;
  const int h0 = (spid & 63) << 1;
  const int o_blk = ohalf << 7;

  const int tid = threadIdx.x;

  // zero the padding columns w'=0 and w'=129 once (first 64B of each line)
  if (tid < 128) {
    const int li = tid >> 5, sel = (tid >> 4) & 1, word = tid & 15;
    const int wq = sel ? 129 : 0;
    *(int*)(Xs + (li * 130 + wq) * LSTRIDE + word * 4) = 0;
  }

  const int wid = tid >> 6, lane = tid & 63;
  const int l15 = lane & 15, g = lane >> 4;
  const int wmo = (wid >> 2) << 6;           // wave o-offset: 0 or 64
  const int wsid = wid & 3, r = wsid >> 1, wbase = (wsid & 1) << 6;

  // staging assignment: thread -> (input row sli, width sw); loads are
  // c-strided per lane but w-contiguous across the wave (256B/instr coalesced)
  const int sw = tid & 127, sli = tid >> 7;
  const int h_in = h0 - 1 + sli;
  const bool inb = (unsigned)h_in < (unsigned)H_;
  const float* xsrc = x + (long)n * (C_ * HW_) + (long)h_in * W_ + sw;
  unsigned char* sdst = Xs + (sli * 130 + sw + 1) * LSTRIDE;

  f32x4 acc[4][4];
  #pragma unroll
  for (int i = 0; i < 4; ++i)
    #pragma unroll
    for (int j = 0; j < 4; ++j) acc[i][j] = (f32x4){0.f, 0.f, 0.f, 0.f};

  for (int c0 = 0; c0 < C_; c0 += 32) {
    // ---- stage: per thread 4x (8 c-strided loads -> pack -> ds_write_b128)
    #pragma unroll
    for (int cg = 0; cg < 4; ++cg) {
      bf16x8 pk = (bf16x8){0, 0, 0, 0, 0, 0, 0, 0};
      if (inb) {
        const float* s = xsrc + (long)(c0 + (cg << 3)) * HW_;
        #pragma unroll
        for (int k = 0; k < 8; ++k)
          pk[k] = (short)__builtin_bit_cast(unsigned short, (__bf16)s[(long)k * HW_]);
      }
      *(bf16x8*)(sdst + (cg << 4)) = pk;
    }
    __syncthreads();

    // ---- compute: 9 kernel taps x (4 mi x 4 ni) MFMA, K=32 (this c-chunk)
    #pragma unroll
    for (int kk = 0; kk < 9; ++kk) {
      const int ky = kk / 3, kx = kk - ky * 3;
      const int li = r + ky;
      const unsigned short* abase =
          wp + ((kk * O_ + o_blk + wmo + l15) * C_) + c0 + (g << 3);
      bf16x8 a[4];
      #pragma unroll
      for (int mi = 0; mi < 4; ++mi)
        a[mi] = *(const bf16x8*)(abase + (mi << 4) * C_);
      #pragma unroll
      for (int ni = 0; ni < 4; ++ni) {
        const int wq = wbase + (ni << 4) + l15 + kx;   // LDS line = input col + 1
        const int byte_off = (li * 130 + wq) * LSTRIDE + (g << 4);
        const bf16x8 b = *(const bf16x8*)(Xs + byte_off);
        #pragma unroll
        for (int mi = 0; mi < 4; ++mi)
          acc[mi][ni] = __builtin_amdgcn_mfma_f32_16x16x32_bf16(a[mi], b, acc[mi][ni], 0, 0, 0);
      }
    }
    __syncthreads();
  }

  // ---- epilogue: out = scale*acc + bias. C/D layout: col = lane&15 (w), row = (lane>>4)*4+q (o)
  const float scale = fmaxf(sum[0] * (1.0f / (float)WELEMS), 1e-5f);
  const int h_out = h0 + r;
  #pragma unroll
  for (int mi = 0; mi < 4; ++mi) {
    #pragma unroll
    for (int q = 0; q < 4; ++q) {
      const int o = o_blk + wmo + (mi << 4) + (g << 2) + q;
      const float bv = bias[o];
      float* orow = out + ((long)n * O_ + o) * (long)HW_ + h_out * W_;
      #pragma unroll
      for (int ni = 0; ni < 4; ++ni) {
        const int wc = wbase + (ni << 4) + l15;
        orow[wc] = acc[mi][ni][q] * scale + bv;
      }
    }
  }
}

extern "C" void kernel_launch(void* const* d_in, const int* in_sizes, int n_in,
                              void* d_out, int out_size, void* d_ws, size_t ws_size,
                              hipStream_t stream) {
  const float* x = (const float*)d_in[0];
  const float* w = (const float*)d_in[1];
  const float* bias = (const float*)d_in[2];
  float* out = (float*)d_out;
  float* sum = (float*)d_ws;
  unsigned short* wp = (unsigned short*)((char*)d_ws + 16);

  hipMemsetAsync(d_ws, 0, 4, stream);
  absum_k<<<256, 256, 0, stream>>>(w, sum);
  quant_k<<<WELEMS / 256, 256, 0, stream>>>(w, sum, wp);
  conv_k<<<2048, 512, 0, stream>>>(x, bias, wp, sum, out);
}